// Round 1
// baseline (3611.459 us; speedup 1.0000x reference)
//
#include <hip/hip_runtime.h>

#define B_ 16
#define C_ 768
#define T_ 1024
#define S_ 12
#define NNEG_ 10
#define COPIES_ 11
#define NPRED_ROWS 195360            // 16 * sum_{s=0..11}(1023-s)
#define NPRED (NPRED_ROWS * COPIES_) // 2148960

// ---------- Kernel 1: W [C][C][S] -> Wt [S][C][C] ----------
__global__ void k_wt(const float* __restrict__ W, float* __restrict__ Wt) {
    int id = blockIdx.x * blockDim.x + threadIdx.x;
    if (id >= C_ * C_) return;
    int c = id / C_, d = id % C_;
    const float* src = W + (size_t)id * S_;
#pragma unroll
    for (int s = 0; s < S_; ++s)
        Wt[(size_t)s * C_ * C_ + (size_t)c * C_ + d] = src[s];
}

// ---------- Kernel 2: y [B][C][T] -> yT [B*T][C] ----------
__global__ void k_yt(const float* __restrict__ y, float* __restrict__ yT) {
    __shared__ float tile[32][33];
    int b = blockIdx.z;
    int c0 = blockIdx.y * 32;
    int t0 = blockIdx.x * 32;
    int tx = threadIdx.x & 31, ty = threadIdx.x >> 5; // 256 thr: ty 0..7
#pragma unroll
    for (int i = 0; i < 4; ++i) {
        int c = c0 + ty + i * 8;
        tile[ty + i * 8][tx] = y[((size_t)b * C_ + c) * T_ + t0 + tx];
    }
    __syncthreads();
#pragma unroll
    for (int i = 0; i < 4; ++i) {
        int t = t0 + ty + i * 8;
        yT[((size_t)b * T_ + t) * C_ + c0 + tx] = tile[tx][ty + i * 8];
    }
}

// ---------- Kernel 3: labels = 0 ----------
__global__ void k_labels(float* __restrict__ out) {
    int i = blockIdx.x * blockDim.x + threadIdx.x;
    if (i < NPRED_ROWS) out[NPRED + i] = 0.0f;
}

// ---------- Main fused kernel ----------
// grid: (T/64, S, B); block: 256 threads.
// Each block: U[64 t][64 d] tile of proj for (b, s), looped over 12 d-tiles;
// epilogue dots U against 11 targets, accumulating p[tt][n] in LDS.
__global__ __launch_bounds__(256) void k_main(
    const float* __restrict__ x, const float* __restrict__ bias,
    const int* __restrict__ neg, const float* __restrict__ Wt,
    const float* __restrict__ yT, float* __restrict__ out)
{
    const int tt0 = blockIdx.x * 64;
    const int s   = blockIdx.y;
    const int b   = blockIdx.z;
    const int tid = threadIdx.x;
    const int tx  = tid & 15;  // d quad: d = d0 + tx*4 + q
    const int ty  = tid >> 4;  // t quad: tt = ty*4 + r

    __shared__ float xs[32][64];
    __shared__ float ws[32][64];
    __shared__ float pacc[64][COPIES_];
    __shared__ int   lidx[64][COPIES_];

    // init p accumulators + target row indices (into yT's [B*T] rows)
    for (int e = tid; e < 64 * COPIES_; e += 256) {
        int tt = e / COPIES_, n = e % COPIES_;
        int t = tt0 + tt;
        int tp = t + s + 1;
        if (tp > T_ - 1) tp = T_ - 1;  // clamp; rows with t >= T-1-s are never written out
        int idx;
        if (n == 0) idx = b * T_ + tp;
        else        idx = neg[(size_t)b * (NNEG_ * T_) + (size_t)(n - 1) * T_ + tp];
        lidx[tt][n] = idx;
        pacc[tt][n] = 0.0f;
    }

    const float* xb   = x  + (size_t)b * C_ * T_ + tt0;
    const float* wsrc = Wt + (size_t)s * C_ * C_;

    float acc[4][4];

    for (int d0 = 0; d0 < C_; d0 += 64) {
#pragma unroll
        for (int r = 0; r < 4; ++r)
#pragma unroll
            for (int q = 0; q < 4; ++q) acc[r][q] = 0.0f;

        for (int c0 = 0; c0 < C_; c0 += 32) {
            __syncthreads();
            {
                int row  = tid >> 3;        // 0..31
                int colq = (tid & 7) * 8;   // 0..56
                const float* xp = xb + (size_t)(c0 + row) * T_ + colq;
                *(float4*)&xs[row][colq]     = *(const float4*)&xp[0];
                *(float4*)&xs[row][colq + 4] = *(const float4*)&xp[4];
                const float* wp = wsrc + (size_t)(c0 + row) * C_ + d0 + colq;
                *(float4*)&ws[row][colq]     = *(const float4*)&wp[0];
                *(float4*)&ws[row][colq + 4] = *(const float4*)&wp[4];
            }
            __syncthreads();
#pragma unroll
            for (int kc = 0; kc < 32; ++kc) {
                float4 xv = *(const float4*)&xs[kc][ty * 4];
                float4 wv = *(const float4*)&ws[kc][tx * 4];
                float xa[4] = {xv.x, xv.y, xv.z, xv.w};
                float wa[4] = {wv.x, wv.y, wv.z, wv.w};
#pragma unroll
                for (int r = 0; r < 4; ++r)
#pragma unroll
                    for (int q = 0; q < 4; ++q)
                        acc[r][q] += xa[r] * wa[q];
            }
        }

        // bias (zeros in practice, but exact): U[tt][d] += b[d], once per (tt,d)
        float4 bv = *(const float4*)&bias[d0 + tx * 4];
        float ba[4] = {bv.x, bv.y, bv.z, bv.w};
#pragma unroll
        for (int r = 0; r < 4; ++r)
#pragma unroll
            for (int q = 0; q < 4; ++q) acc[r][q] += ba[q];

        // epilogue: partial dots against 11 targets over this d-tile
#pragma unroll
        for (int r = 0; r < 4; ++r) {
            int tt = ty * 4 + r;
#pragma unroll
            for (int n = 0; n < COPIES_; ++n) {
                int idx = lidx[tt][n];
                const float4 tv = *(const float4*)&yT[(size_t)idx * C_ + d0 + tx * 4];
                float pp = acc[r][0] * tv.x + acc[r][1] * tv.y +
                           acc[r][2] * tv.z + acc[r][3] * tv.w;
                pp += __shfl_xor(pp, 1);
                pp += __shfl_xor(pp, 2);
                pp += __shfl_xor(pp, 4);
                pp += __shfl_xor(pp, 8);
                if (tx == 0) pacc[tt][n] += pp;  // unique (tt,n) writer per block
            }
        }
    }

    __syncthreads();
    // flat row = B * sum_{j<s}(T-1-j) + t*B + b ; out[row*COPIES + n]
    const int rowbase = s * (T_ - 1) - (s * (s - 1)) / 2;
    const int tmax = T_ - 1 - s;
    for (int e = tid; e < 64 * COPIES_; e += 256) {
        int tt = e / COPIES_, n = e % COPIES_;
        int t = tt0 + tt;
        if (t < tmax) {
            size_t row = (size_t)(rowbase + t) * B_ + b;
            out[row * COPIES_ + n] = pacc[tt][n];
        }
    }
}

extern "C" void kernel_launch(void* const* d_in, const int* in_sizes, int n_in,
                              void* d_out, int out_size, void* d_ws, size_t ws_size,
                              hipStream_t stream) {
    const float* x    = (const float*)d_in[0];
    const float* y    = (const float*)d_in[1];
    const float* W    = (const float*)d_in[2];
    const float* bias = (const float*)d_in[3];
    const int*   neg  = (const int*)d_in[4];
    float* out = (float*)d_out;

    // ws layout: Wt (S*C*C floats = 28.3 MB) | yT (B*T*C floats = 50.3 MB)
    float* Wt = (float*)d_ws;
    float* yT = Wt + (size_t)S_ * C_ * C_;

    k_wt<<<dim3((C_ * C_ + 255) / 256), 256, 0, stream>>>(W, Wt);
    k_yt<<<dim3(T_ / 32, C_ / 32, B_), 256, 0, stream>>>(y, yT);
    k_labels<<<dim3((NPRED_ROWS + 255) / 256), 256, 0, stream>>>(out);
    k_main<<<dim3(T_ / 64, S_, B_), 256, 0, stream>>>(x, bias, neg, Wt, yT, out);
}

// Round 2
// 696.969 us; speedup vs baseline: 5.1817x; 5.1817x over previous
//
#include <hip/hip_runtime.h>

typedef __bf16 bf16;
typedef __attribute__((ext_vector_type(8))) __bf16 bf16x8;
typedef __attribute__((ext_vector_type(4))) float f32x4;

#define B_ 16
#define C_ 768
#define T_ 1024
#define S_ 12
#define NNEG_ 10
#define NCOPY 11
#define NPRED_ROWS 195360            // 16 * sum_{s=0..11}(1023-s)
#define NPRED (NPRED_ROWS * NCOPY)   // 2148960

__device__ __forceinline__ void gload16(const void* g, void* l) {
    __builtin_amdgcn_global_load_lds(
        (__attribute__((address_space(1))) void*)g,
        (__attribute__((address_space(3))) void*)l, 16, 0, 0);
}

// ---------- W [C][C][S] fp32 -> WtT [S][D=C][C] bf16 ----------
__global__ void k_wt(const float* __restrict__ W, bf16* __restrict__ WtT) {
    int id = blockIdx.x * blockDim.x + threadIdx.x;   // id = d*768 + c
    if (id >= C_ * C_) return;
    int d = id / C_, c = id % C_;
    const float* src = W + ((size_t)c * C_ + d) * S_;
#pragma unroll
    for (int s = 0; s < S_; ++s)
        WtT[(size_t)s * C_ * C_ + id] = (bf16)src[s];
}

// ---------- src [16][C][T] fp32 (batch b0+bz) -> dst [cb][T][C] bf16 ----------
__global__ void k_tr(const float* __restrict__ src, bf16* __restrict__ dst, int b0) {
    __shared__ float tile[32][33];
    int bb = blockIdx.z;
    int b = b0 + bb;
    int c0 = blockIdx.y * 32, t0 = blockIdx.x * 32;
    int tx = threadIdx.x & 31, ty = threadIdx.x >> 5;  // ty 0..7
#pragma unroll
    for (int i = 0; i < 4; ++i)
        tile[ty + i * 8][tx] = src[((size_t)b * C_ + c0 + ty + i * 8) * T_ + t0 + tx];
    __syncthreads();
#pragma unroll
    for (int i = 0; i < 4; ++i)
        dst[((size_t)bb * T_ + t0 + ty + i * 8) * C_ + c0 + tx] = (bf16)tile[tx][ty + i * 8];
}

// ---------- labels = 0 ----------
__global__ void k_labels(float* __restrict__ out) {
    int i = blockIdx.x * blockDim.x + threadIdx.x;
    if (i < NPRED_ROWS) out[NPRED + i] = 0.0f;
}

// ---------- Phase 1: proj[bb][t][s*768+d] = sum_c xT[bb][t][c]*WtT[s][d][c] + bias[d]
// grid (72, 8, cb), 256 threads. 128x128 tile, BK=32, MFMA 16x16x32 bf16.
__global__ __launch_bounds__(256) void k_gemm(
    const bf16* __restrict__ xTc, const bf16* __restrict__ WtT,
    const float* __restrict__ bias, bf16* __restrict__ P)
{
    const int nblk = blockIdx.x;   // 0..71  (n = nblk*128.., n = s*768+d)
    const int mblk = blockIdx.y;   // 0..7   (t)
    const int bb   = blockIdx.z;
    const int tid  = threadIdx.x;
    const int wave = tid >> 6, lane = tid & 63;
    const int mw = wave >> 1, nw = wave & 1;
    const int quad = lane >> 4, l15 = lane & 15;

    // fragment-major LDS: group g holds a 16m x 32k tile in lane-slot order
    __shared__ __align__(16) bf16 sA[8][64][8];
    __shared__ __align__(16) bf16 sB[8][64][8];

    const int col = quad * 8;
    const int rA0 = mblk * 128 + (2 * wave) * 16 + l15;
    const int rB0 = nblk * 128 + (2 * wave) * 16 + l15;
    const bf16* gA0 = xTc + ((size_t)bb * T_ + rA0) * C_ + col;
    const bf16* gA1 = gA0 + (size_t)16 * C_;
    const bf16* gB0 = WtT + (size_t)rB0 * C_ + col;
    const bf16* gB1 = gB0 + (size_t)16 * C_;

    f32x4 acc[4][4] = {};

    for (int k0 = 0; k0 < C_; k0 += 32) {
        __syncthreads();
        gload16(gA0 + k0, &sA[2 * wave][0][0]);
        gload16(gA1 + k0, &sA[2 * wave + 1][0][0]);
        gload16(gB0 + k0, &sB[2 * wave][0][0]);
        gload16(gB1 + k0, &sB[2 * wave + 1][0][0]);
        __syncthreads();

        bf16x8 af[4], bfr[4];
#pragma unroll
        for (int i = 0; i < 4; ++i) af[i]  = *(const bf16x8*)&sA[mw * 4 + i][lane][0];
#pragma unroll
        for (int j = 0; j < 4; ++j) bfr[j] = *(const bf16x8*)&sB[nw * 4 + j][lane][0];
#pragma unroll
        for (int i = 0; i < 4; ++i)
#pragma unroll
            for (int j = 0; j < 4; ++j)
                acc[i][j] = __builtin_amdgcn_mfma_f32_16x16x32_bf16(af[i], bfr[j], acc[i][j], 0, 0, 0);
    }

    // epilogue: add bias[d], store bf16. C/D: col = lane&15, row = quad*4+reg.
#pragma unroll
    for (int i = 0; i < 4; ++i) {
        int m = mblk * 128 + (mw * 4 + i) * 16 + quad * 4;
#pragma unroll
        for (int j = 0; j < 4; ++j) {
            int nl = (nw * 4 + j) * 16 + l15;
            float bv = bias[(nblk % 6) * 128 + nl];
            size_t base = ((size_t)bb * T_ + m) * (size_t)(S_ * C_) + (size_t)nblk * 128 + nl;
#pragma unroll
            for (int r = 0; r < 4; ++r)
                P[base + (size_t)r * (S_ * C_)] = (bf16)(acc[i][j][r] + bv);
        }
    }
}

// ---------- Phase 2: one wave per (bb, tp). p[s][n] = sum_d proj[t=tp-1-s][s][d]*tar[n][d]
__global__ __launch_bounds__(256) void k_pred(
    const bf16* __restrict__ P, const bf16* __restrict__ yTc,
    const int* __restrict__ neg, float* __restrict__ out, int b0)
{
    const int widx = (blockIdx.x << 2) + (threadIdx.x >> 6);
    const int lane = threadIdx.x & 63;
    const int bb = widx >> 10, tp = widx & 1023;
    const int b = b0 + bb;
    const int quad = lane >> 4, l15 = lane & 15;

    // A row: m = s (pad rows clamped; their outputs are never stored)
    int sA = l15 < S_ ? l15 : S_ - 1;
    int tA = tp - 1 - sA;
    if (tA < 0) tA = 0;
    const bf16* arow = P + ((size_t)bb * T_ + tA) * (S_ * C_) + sA * C_ + quad * 8;

    // B row: n = copy (pad clamped)
    int ridx;
    if (l15 == 0)            ridx = bb * T_ + tp;
    else if (l15 < NCOPY)    ridx = neg[(size_t)b * (NNEG_ * T_) + (l15 - 1) * T_ + tp] - b0 * T_;
    else                     ridx = bb * T_ + tp;
    const bf16* brow = yTc + (size_t)ridx * C_ + quad * 8;

    f32x4 acc = {};
#pragma unroll 4
    for (int kt = 0; kt < C_ / 32; ++kt) {
        bf16x8 av = *(const bf16x8*)(arow + kt * 32);
        bf16x8 bv = *(const bf16x8*)(brow + kt * 32);
        acc = __builtin_amdgcn_mfma_f32_16x16x32_bf16(av, bv, acc, 0, 0, 0);
    }

    if (l15 < NCOPY) {
#pragma unroll
        for (int r = 0; r < 4; ++r) {
            int s = quad * 4 + r;
            int t = tp - 1 - s;
            if (s < S_ && t >= 0) {
                int rowbase = s * (T_ - 1) - (s * (s - 1)) / 2;
                out[(((size_t)(rowbase + t)) * B_ + b) * NCOPY + l15] = acc[r];
            }
        }
    }
}

extern "C" void kernel_launch(void* const* d_in, const int* in_sizes, int n_in,
                              void* d_out, int out_size, void* d_ws, size_t ws_size,
                              hipStream_t stream) {
    const float* x    = (const float*)d_in[0];
    const float* y    = (const float*)d_in[1];
    const float* W    = (const float*)d_in[2];
    const float* bias = (const float*)d_in[3];
    const int*   neg  = (const int*)d_in[4];
    float* out = (float*)d_out;

    const size_t offW    = (size_t)S_ * C_ * C_ * 2;        // 14,155,776
    const size_t perb_xy = (size_t)T_ * C_ * 2;             // 1,572,864
    const size_t perb_p  = (size_t)T_ * S_ * C_ * 2;        // 18,874,368
    const size_t perb    = 2 * perb_xy + perb_p;

    int bchunk = (int)((ws_size - offW) / perb);
    if (bchunk < 1) bchunk = 1;            // round-1 proved ws >= 78.6MB, so >=2 in practice
    if (bchunk > B_) bchunk = B_;

    char* ws = (char*)d_ws;
    bf16* WtT = (bf16*)ws;
    bf16* xTc = (bf16*)(ws + offW);
    bf16* yTc = (bf16*)(ws + offW + (size_t)bchunk * perb_xy);
    bf16* P   = (bf16*)(ws + offW + (size_t)bchunk * perb_xy * 2);

    k_wt<<<dim3((C_ * C_ + 255) / 256), 256, 0, stream>>>(W, WtT);
    k_labels<<<dim3((NPRED_ROWS + 255) / 256), 256, 0, stream>>>(out);

    for (int b0 = 0; b0 < B_;) {
        int cb = bchunk < (B_ - b0) ? bchunk : (B_ - b0);
        k_tr<<<dim3(T_ / 32, C_ / 32, cb), 256, 0, stream>>>(x, xTc, b0);
        k_tr<<<dim3(T_ / 32, C_ / 32, cb), 256, 0, stream>>>(y, yTc, b0);
        k_gemm<<<dim3(72, 8, cb), 256, 0, stream>>>(xTc, WtT, bias, P);
        k_pred<<<dim3(cb * 256), 256, 0, stream>>>(P, yTc, neg, out, b0);
        b0 += cb;
    }
}